// Round 17
// baseline (407.086 us; speedup 1.0000x reference)
//
#include <hip/hip_runtime.h>

// Problem constants
#define N_ROWS 32768   // 8*4096
#define DIM    256
#define KCODES 8192
#define DECAYF 0.8f
#define OMDF   0.2f
#define EPSF   1e-5f

// d_out layout (float element offsets)
#define Q_OFF    0
#define IND_OFF  8388608
#define CS_OFF   8421376
#define EA_OFF   8429568
#define NE_OFF   10526720

// Scratch: Xp -> Q first half; rowlist -> Q second half; gbest -> EA head;
// Ep -> EA + 65536 floats. Same proven placement as r10-r16.

// ws layout: e2 f32[8192], cnt i32[8192], start i32[8192], cursor i32[8192],
// sum f32[1]
#define WS_E2    0
#define WS_CNT   8192
#define WS_START 16384
#define WS_CUR   24576
#define WS_SUM   40960

typedef _Float16 half8 __attribute__((ext_vector_type(8)));
typedef float floatx16 __attribute__((ext_vector_type(16)));

// ---------------------------------------------------------------------------
// prep_all (r10-verified, unchanged)
#define PREP_ROWS 32
__global__ void prep_all_kernel(const float* __restrict__ x,
                                const float* __restrict__ embed,
                                const float* __restrict__ cs,
                                _Float16* __restrict__ Xp,
                                _Float16* __restrict__ Ep,
                                float* __restrict__ out,
                                float* __restrict__ ws) {
  __shared__ __align__(16) _Float16 L[PREP_ROWS][264];
  __shared__ float red[4];
  const int t = threadIdx.x;
  const int bid = blockIdx.x;

  if (bid < 1024) {
    if (bid < 128) {
      unsigned long long* gbest = (unsigned long long*)(out + EA_OFF);
      gbest[bid * 256 + t] = 0ULL;
    } else if (bid < 160) {
      ((int*)(ws + WS_CNT))[(bid - 128) * 256 + t] = 0;
    }
    const int row0 = bid * PREP_ROWS;
    #pragma unroll
    for (int it = 0; it < 8; ++it) {
      int idx = it * 256 + t;
      int r = idx >> 6, q = idx & 63;
      float4 v = *(const float4*)&x[(size_t)(row0 + r) * DIM + q * 4];
      L[r][q * 4 + 0] = (_Float16)v.x;
      L[r][q * 4 + 1] = (_Float16)v.y;
      L[r][q * 4 + 2] = (_Float16)v.z;
      L[r][q * 4 + 3] = (_Float16)v.w;
    }
    __syncthreads();
    #pragma unroll
    for (int it = 0; it < 4; ++it) {
      int idx = it * 256 + t;
      int slot = idx >> 5, r = idx & 31;
      *(float4*)&Xp[((size_t)slot * N_ROWS + row0 + r) * 8] =
          *(const float4*)&L[r][slot * 8];
    }
  } else {
    const int row0 = (bid - 1024) * PREP_ROWS;
    float* e2 = ws + WS_E2;
    #pragma unroll
    for (int it = 0; it < 8; ++it) {
      int idx = it * 256 + t;
      int r = idx >> 6, q = idx & 63;
      float4 v = *(const float4*)&embed[(size_t)(row0 + r) * DIM + q * 4];
      L[r][q * 4 + 0] = (_Float16)v.x;
      L[r][q * 4 + 1] = (_Float16)v.y;
      L[r][q * 4 + 2] = (_Float16)v.z;
      L[r][q * 4 + 3] = (_Float16)v.w;
      float ssq = v.x * v.x + v.y * v.y + v.z * v.z + v.w * v.w;
      #pragma unroll
      for (int o = 32; o; o >>= 1) ssq += __shfl_xor(ssq, o);
      if ((t & 63) == 0) e2[row0 + r] = ssq;
    }
    if (bid == 1024) {
      float s = 0.0f;
      for (int j = t; j < KCODES; j += 256) s += cs[j];
      #pragma unroll
      for (int o = 32; o; o >>= 1) s += __shfl_xor(s, o);
      if ((t & 63) == 0) red[t >> 6] = s;
    }
    __syncthreads();
    if (bid == 1024 && t == 0)
      ws[WS_SUM] = red[0] + red[1] + red[2] + red[3];
    #pragma unroll
    for (int it = 0; it < 4; ++it) {
      int idx = it * 256 + t;
      int slot = idx >> 5, r = idx & 31;
      *(float4*)&Ep[((size_t)slot * KCODES + row0 + r) * 8] =
          *(const float4*)&L[r][slot * 8];
    }
  }
}

// ---------------------------------------------------------------------------
// Main MFMA kernel — BARRIER-FREE, LDS-FREE. Pure-hi GEMM K=256.
// Each wave is an independent dataflow pipeline: fragments are loaded
// directly from Ep/Xp (L1/L2-resident; per-block unique = 16KB/step) into a
// register double-buffer; per K16-step {8 MFMA on buf p -> prefetch j+2}.
// No __shared__, no s_barrier, no manual vmcnt. Lane addressing replicates
// r13's LDS-read mapping exactly (same data, same k-order -> same numerics).
// Block 256 codes x 256 rows, 8 waves (2Mx4N), wave tile 128x64.
__global__ __launch_bounds__(512, 2) void main_kernel(
    const _Float16* __restrict__ Xp, const _Float16* __restrict__ Ep,
    const float* __restrict__ e2, unsigned long long* __restrict__ gbest) {
  const int t = threadIdx.x;
  const int w = t >> 6;
  const int lane = t & 63;
  const int l31 = lane & 31;
  const int h = lane >> 5;
  const int wm = w >> 2;   // code half 0..1
  const int wn = w & 3;    // row quarter 0..3

  // XCD-grouped mapping: xcd = bid&7 owns cb in [4*xcd,4*xcd+4), rb-fastest.
  const int bid = blockIdx.x;
  const int bi = bid >> 3;
  const int cb = (bid & 7) * 4 + (bi >> 7);  // 0..31
  const int rb = bi & 127;                   // 0..127
  const int codes0 = cb * 256;
  const int row0 = rb * 256;

  // fragment base pointers; k-group for step j, parity h: kg = 2*j + h
  const _Float16* aB = Ep + ((size_t)h * KCODES + codes0 + wm * 128 + l31) * 8;
  const _Float16* bB = Xp + ((size_t)h * N_ROWS + row0 + wn * 64 + l31) * 8;
  const size_t aStep = (size_t)2 * KCODES * 8;
  const size_t bStep = (size_t)2 * N_ROWS * 8;

  // acc init = -0.5 * e2[code]  (L2-hot reads, once per block)
  floatx16 acc[4][2];
  #pragma unroll
  for (int ct = 0; ct < 4; ++ct) {
    const int cbase = codes0 + wm * 128 + ct * 32 + 4 * h;
    #pragma unroll
    for (int rq = 0; rq < 4; ++rq) {
      float4 v = *(const float4*)&e2[cbase + rq * 8];
      acc[ct][0][rq * 4 + 0] = -0.5f * v.x;
      acc[ct][0][rq * 4 + 1] = -0.5f * v.y;
      acc[ct][0][rq * 4 + 2] = -0.5f * v.z;
      acc[ct][0][rq * 4 + 3] = -0.5f * v.w;
    }
    acc[ct][1] = acc[ct][0];
  }

  // register double-buffer; indices compile-time after full unroll (rule #20)
  half8 A[2][4], B[2][2];
  #pragma unroll
  for (int p = 0; p < 2; ++p) {
    #pragma unroll
    for (int f = 0; f < 4; ++f)
      A[p][f] = *(const half8*)(aB + (size_t)p * aStep + f * 32 * 8);
    B[p][0] = *(const half8*)(bB + (size_t)p * bStep);
    B[p][1] = *(const half8*)(bB + (size_t)p * bStep + 32 * 8);
  }

  #pragma unroll
  for (int j = 0; j < 16; ++j) {
    const int p = j & 1;
    __builtin_amdgcn_s_setprio(1);
    acc[0][0] = __builtin_amdgcn_mfma_f32_32x32x16_f16(A[p][0], B[p][0], acc[0][0], 0, 0, 0);
    acc[0][1] = __builtin_amdgcn_mfma_f32_32x32x16_f16(A[p][0], B[p][1], acc[0][1], 0, 0, 0);
    acc[1][0] = __builtin_amdgcn_mfma_f32_32x32x16_f16(A[p][1], B[p][0], acc[1][0], 0, 0, 0);
    acc[1][1] = __builtin_amdgcn_mfma_f32_32x32x16_f16(A[p][1], B[p][1], acc[1][1], 0, 0, 0);
    acc[2][0] = __builtin_amdgcn_mfma_f32_32x32x16_f16(A[p][2], B[p][0], acc[2][0], 0, 0, 0);
    acc[2][1] = __builtin_amdgcn_mfma_f32_32x32x16_f16(A[p][2], B[p][1], acc[2][1], 0, 0, 0);
    acc[3][0] = __builtin_amdgcn_mfma_f32_32x32x16_f16(A[p][3], B[p][0], acc[3][0], 0, 0, 0);
    acc[3][1] = __builtin_amdgcn_mfma_f32_32x32x16_f16(A[p][3], B[p][1], acc[3][1], 0, 0, 0);
    __builtin_amdgcn_s_setprio(0);
    if (j + 2 < 16) {
      const size_t ja = (size_t)(j + 2) * aStep;
      const size_t jb = (size_t)(j + 2) * bStep;
      #pragma unroll
      for (int f = 0; f < 4; ++f)
        A[p][f] = *(const half8*)(aB + ja + f * 32 * 8);
      B[p][0] = *(const half8*)(bB + jb);
      B[p][1] = *(const half8*)(bB + jb + 32 * 8);
    }
  }

  // epilogue: lane-local argmax -> h-pair shfl combine -> global atomicMax
  // C layout (32x32): col(xrow)=lane&31, row(code)=(r&3)+8*(r>>2)+4*h
  #pragma unroll
  for (int rt = 0; rt < 2; ++rt) {
    float best = -3.0e38f;
    int bidx = 0;
    #pragma unroll
    for (int ct = 0; ct < 4; ++ct) {
      const int cbase = codes0 + wm * 128 + ct * 32 + 4 * h;
      #pragma unroll
      for (int r = 0; r < 16; ++r) {
        const int code = cbase + (r & 3) + 8 * (r >> 2);
        float v = acc[ct][rt][r];
        if (v > best || (v == best && code < bidx)) { best = v; bidx = code; }
      }
    }
    unsigned u = __float_as_uint(best);
    u = (u & 0x80000000u) ? ~u : (u | 0x80000000u);
    unsigned long long p =
        ((unsigned long long)u << 32) | (unsigned)(8191 - bidx);
    unsigned long long op = (unsigned long long)__shfl_xor((long long)p, 32);
    if (op > p) p = op;
    if (h == 0)
      atomicMax(&gbest[row0 + wn * 64 + rt * 32 + l31], p);
  }
}

// ---------------------------------------------------------------------------
// decode_count: gbest -> IND + cnt histogram. Last reader of gbest.
__global__ void decode_count_kernel(const unsigned long long* __restrict__ gbest,
                                    float* __restrict__ out,
                                    int* __restrict__ cnt) {
  int r = blockIdx.x * blockDim.x + threadIdx.x;  // 32768 threads
  unsigned long long p = gbest[r];
  int k = 8191 - (int)(unsigned)(p & 0xFFFFFFFFull);
  out[IND_OFF + r] = (float)k;
  atomicAdd(&cnt[k], 1);
}

// ---------------------------------------------------------------------------
__global__ void prefix_kernel(const int* __restrict__ cnt,
                              int* __restrict__ start,
                              int* __restrict__ cursor) {
  __shared__ int part[1024];
  const int t = threadIdx.x;
  int loc[8];
  int s = 0;
  #pragma unroll
  for (int j = 0; j < 8; ++j) { loc[j] = cnt[t * 8 + j]; s += loc[j]; }
  part[t] = s;
  __syncthreads();
  for (int off = 1; off < 1024; off <<= 1) {
    int v = (t >= off) ? part[t - off] : 0;
    __syncthreads();
    part[t] += v;
    __syncthreads();
  }
  int base = part[t] - s;
  #pragma unroll
  for (int j = 0; j < 8; ++j) {
    start[t * 8 + j] = base;
    cursor[t * 8 + j] = base;
    base += loc[j];
  }
}

// ---------------------------------------------------------------------------
__global__ void scatter_rows_kernel(const float* __restrict__ out,
                                    int* __restrict__ cursor,
                                    int* __restrict__ rowlist) {
  int r = blockIdx.x * blockDim.x + threadIdx.x;  // 32768 threads
  int k = (int)out[IND_OFF + r];
  int pos = atomicAdd(&cursor[k], 1);
  rowlist[pos] = r;
}

// ---------------------------------------------------------------------------
__global__ void bucket_final_kernel(const float* __restrict__ x,
                                    const float* __restrict__ cs,
                                    const float* __restrict__ embed_avg,
                                    const int* __restrict__ start,
                                    const int* __restrict__ cnt,
                                    const int* __restrict__ rowlist,
                                    float* __restrict__ out,
                                    const float* __restrict__ ws_sum) {
  const int lane = threadIdx.x & 63;
  const int k = blockIdx.x * 4 + (threadIdx.x >> 6);
  const int s = start[k];
  const int n = cnt[k];
  float4 acc = make_float4(0.f, 0.f, 0.f, 0.f);
  int i = 0;
  for (; i + 2 <= n; i += 2) {
    int r0 = rowlist[s + i];
    int r1 = rowlist[s + i + 1];
    float4 v0 = *(const float4*)&x[(size_t)r0 * DIM + lane * 4];
    float4 v1 = *(const float4*)&x[(size_t)r1 * DIM + lane * 4];
    acc.x += v0.x + v1.x; acc.y += v0.y + v1.y;
    acc.z += v0.z + v1.z; acc.w += v0.w + v1.w;
  }
  if (i < n) {
    int r0 = rowlist[s + i];
    float4 v0 = *(const float4*)&x[(size_t)r0 * DIM + lane * 4];
    acc.x += v0.x; acc.y += v0.y; acc.z += v0.z; acc.w += v0.w;
  }
  const float S = DECAYF * (*ws_sum) + OMDF * (float)N_ROWS;
  const float scale = S / (S + (float)KCODES * EPSF);
  float ncs = cs[k] * DECAYF + (float)n * OMDF;
  if (lane == 0) out[CS_OFF + k] = ncs;
  float4 ea = *(const float4*)&embed_avg[(size_t)k * DIM + lane * 4];
  float4 nea;
  nea.x = ea.x * DECAYF + acc.x * OMDF;
  nea.y = ea.y * DECAYF + acc.y * OMDF;
  nea.z = ea.z * DECAYF + acc.z * OMDF;
  nea.w = ea.w * DECAYF + acc.w * OMDF;
  *(float4*)&out[EA_OFF + (size_t)k * DIM + lane * 4] = nea;
  float inv_sm = 1.0f / ((ncs + EPSF) * scale);
  float4 ne;
  ne.x = nea.x * inv_sm;
  ne.y = nea.y * inv_sm;
  ne.z = nea.z * inv_sm;
  ne.w = nea.w * inv_sm;
  *(float4*)&out[NE_OFF + (size_t)k * DIM + lane * 4] = ne;
}

// ---------------------------------------------------------------------------
__global__ void finish_q_kernel(const float* __restrict__ embed,
                                float* __restrict__ out) {
  const int lane = threadIdx.x & 63;
  const int wave = (blockIdx.x * blockDim.x + threadIdx.x) >> 6;  // 0..2047
  for (int row = wave; row < N_ROWS; row += 2048) {
    int k = (int)out[IND_OFF + row];
    float4 ev = *(const float4*)&embed[(size_t)k * DIM + lane * 4];
    *(float4*)&out[Q_OFF + (size_t)row * DIM + lane * 4] = ev;
  }
}

// ---------------------------------------------------------------------------
extern "C" void kernel_launch(void* const* d_in, const int* in_sizes, int n_in,
                              void* d_out, int out_size, void* d_ws, size_t ws_size,
                              hipStream_t stream) {
  const float* x = (const float*)d_in[0];
  const float* embed = (const float*)d_in[1];
  const float* cs = (const float*)d_in[2];
  const float* ea = (const float*)d_in[3];
  float* out = (float*)d_out;
  float* ws = (float*)d_ws;

  float* e2 = ws + WS_E2;
  int* cnt = (int*)(ws + WS_CNT);
  int* start = (int*)(ws + WS_START);
  int* cursor = (int*)(ws + WS_CUR);
  float* ws_sum = ws + WS_SUM;

  _Float16* Xp = (_Float16*)(out + Q_OFF);                          // 16 MB
  int* rowlist = (int*)(out + Q_OFF + 4194304);                     // Q dead half
  unsigned long long* gbest = (unsigned long long*)(out + EA_OFF);  // 256 KB
  _Float16* Ep = (_Float16*)(out + EA_OFF + 65536);                 // 4 MB

  prep_all_kernel<<<1280, 256, 0, stream>>>(x, embed, cs, Xp, Ep, out, ws);
  main_kernel<<<4096, 512, 0, stream>>>(Xp, Ep, e2, gbest);
  decode_count_kernel<<<128, 256, 0, stream>>>(gbest, out, cnt);
  prefix_kernel<<<1, 1024, 0, stream>>>(cnt, start, cursor);
  scatter_rows_kernel<<<128, 256, 0, stream>>>(out, cursor, rowlist);
  bucket_final_kernel<<<2048, 256, 0, stream>>>(x, cs, ea, start, cnt,
                                                rowlist, out, ws_sum);
  finish_q_kernel<<<512, 256, 0, stream>>>(embed, out);
}